// Round 8
// baseline (303.483 us; speedup 1.0000x reference)
//
#include <hip/hip_runtime.h>
#include <hip/hip_bf16.h>

#define D 128

typedef __bf16 bf16x8 __attribute__((ext_vector_type(8)));
typedef unsigned short u16x8 __attribute__((ext_vector_type(8)));
typedef float f32x4 __attribute__((ext_vector_type(4)));

__device__ __forceinline__ unsigned short f2bf(float f) {
    unsigned u = __float_as_uint(f);
    u += 0x7FFFu + ((u >> 16) & 1u);
    return (unsigned short)(u >> 16);
}
__device__ __forceinline__ float bf2f(unsigned u16) {
    return __uint_as_float(u16 << 16);
}

// Build W = [W_nbrs | W_self]^T as bf16, XOR-swizzled so the GEMMs can stage it
// linearly into LDS and read B fragments conflict-free.
// Element (k, c) -> WTs[c*128 + (((k>>3) ^ (c&15)) << 3) + (k&7)]
// Also zeroes cnt[] (replaces a separate memset dispatch).
__global__ void k_build_wt(const float* __restrict__ Wn, const float* __restrict__ Ws,
                           unsigned short* __restrict__ WTs,
                           int* __restrict__ cnt, int N) {
    int g = blockIdx.x * blockDim.x + threadIdx.x;   // 0..32767
    int k = g >> 8;          // 0..127
    int c = g & 255;         // 0..255 (coalesced reads along c)
    float v = (c < 128) ? Wn[k * 128 + c] : Ws[k * 128 + (c - 128)];
    int chunk = k >> 3;
    WTs[c * 128 + (((chunk ^ (c & 15)) << 3) | (k & 7))] = f2bf(v);
    for (int i = g; i < N; i += 32768) cnt[i] = 0;
}

// k1: EVERY block does gemm_y (64 rows) AND rank (1024 edges).
// Edge loads issue before the staging barrier (free: barrier drains anyway);
// atomics issue AFTER the barrier so they overlap the MFMA phase; rank
// results are stored at the end, by which time the returns have arrived.
__global__ __launch_bounds__(256) void k1_gemm_y_rank(
    const float* __restrict__ x, const unsigned short* __restrict__ WTs, int N,
    unsigned short* __restrict__ y,
    const int* __restrict__ edst, int E,
    int* __restrict__ cnt, int* __restrict__ rank) {
    __shared__ unsigned short sm[128 * 128];   // 32 KB (B0 half)
    int b = blockIdx.x;
    int tid = threadIdx.x;
    int e0 = b * 1024 + tid * 4;
    bool efull = (e0 + 3 < E);
    bool etail = !efull && (e0 < E);
    int4 d4 = make_int4(0, 0, 0, 0);
    if (efull) d4 = *(const int4*)(edst + e0);   // coalesced, early

    int brow = b * 64;
    bool gvalid = (brow < N);                    // block-uniform
    int w = tid >> 6, l = tid & 63;
    int c15 = l & 15;
    int kgrp = l >> 4;
    bf16x8 afrag[4];
    if (gvalid) {
        const uint4* gs = (const uint4*)WTs;
        uint4* ss = (uint4*)sm;
        uint4 st[8];
        #pragma unroll
        for (int r = 0; r < 8; ++r) st[r] = gs[r * 256 + tid];   // B0 half
        int row0 = brow + w * 16;
        int arow = row0 + c15;                   // A: row = lane%16
        bool avalid = (arow < N);
        const float* xr = x + (size_t)arow * D;
        #pragma unroll
        for (int ks = 0; ks < 4; ++ks) {
            int k0 = ks * 32 + kgrp * 8;         // A: k = 8*(lane/16) + j
            float4 a0, a1;
            if (avalid) { a0 = *(const float4*)(xr + k0); a1 = *(const float4*)(xr + k0 + 4); }
            else { a0 = make_float4(0.f, 0.f, 0.f, 0.f); a1 = a0; }
            bf16x8 f;
            f[0] = (__bf16)a0.x; f[1] = (__bf16)a0.y; f[2] = (__bf16)a0.z; f[3] = (__bf16)a0.w;
            f[4] = (__bf16)a1.x; f[5] = (__bf16)a1.y; f[6] = (__bf16)a1.z; f[7] = (__bf16)a1.w;
            afrag[ks] = f;
        }
        #pragma unroll
        for (int r = 0; r < 8; ++r) ss[r * 256 + tid] = st[r];
        __syncthreads();
    }
    // atomics issued post-barrier: overlap the MFMA phase below
    int r0 = 0, r1 = 0, r2 = 0, r3 = 0;
    if (efull) {
        r0 = atomicAdd(&cnt[d4.x], 1);
        r1 = atomicAdd(&cnt[d4.y], 1);
        r2 = atomicAdd(&cnt[d4.z], 1);
        r3 = atomicAdd(&cnt[d4.w], 1);
    }
    if (gvalid) {
        f32x4 acc[8];
        #pragma unroll
        for (int nt = 0; nt < 8; ++nt) {
            int c = nt * 16 + c15;
            f32x4 a = {0.f, 0.f, 0.f, 0.f};
            #pragma unroll
            for (int ks = 0; ks < 4; ++ks) {
                int chunk = ks * 4 + kgrp;
                const bf16x8* bp = (const bf16x8*)(sm + c * 128 + ((chunk ^ c15) << 3));
                a = __builtin_amdgcn_mfma_f32_16x16x32_bf16(afrag[ks], *bp, a, 0, 0, 0);
            }
            acc[nt] = a;
        }
        int orow = brow + w * 16 + kgrp * 4;     // C/D: row = 4*(lane/16) + j
        #pragma unroll
        for (int j = 0; j < 4; ++j) {            // permuted 16-B stores
            int r = orow + j;
            if (r < N) {
                u16x8 f;
                #pragma unroll
                for (int nt = 0; nt < 8; ++nt) f[nt] = f2bf(acc[nt][j]);
                *(u16x8*)(y + (size_t)r * D + c15 * 8) = f;
            }
        }
    }
    if (efull) {
        *(int4*)(rank + e0) = make_int4(r0, r1, r2, r3);
    } else if (etail) {
        for (int e = e0; e < E; ++e) rank[e] = atomicAdd(&cnt[edst[e]], 1);
    }
}

// shfl-based scan: 2 barriers instead of 20.
__global__ void k_scanA(const int* __restrict__ cnt, int N,
                        int* __restrict__ ofs, int* __restrict__ bsum) {
    __shared__ int ws[16];
    int t = threadIdx.x, i = blockIdx.x * 1024 + t;
    int v = (i < N) ? cnt[i] : 0;
    int s = v;                                   // inclusive scan within wave
    #pragma unroll
    for (int d = 1; d < 64; d <<= 1) {
        int xp = __shfl_up(s, d, 64);
        if ((t & 63) >= d) s += xp;
    }
    int wid = t >> 6;
    if ((t & 63) == 63) ws[wid] = s;
    __syncthreads();
    if (wid == 0) {
        int wv = (t < 16) ? ws[t] : 0;
        #pragma unroll
        for (int d = 1; d < 16; d <<= 1) {
            int xp = __shfl_up(wv, d, 64);
            if (t >= d && t < 16) wv += xp;
        }
        if (t < 16) ws[t] = wv;                  // inclusive wave-sum scan
    }
    __syncthreads();
    int base = (wid > 0) ? ws[wid - 1] : 0;
    int incl = s + base;
    if (i < N) ofs[i] = incl - v;                // local exclusive scan
    if (t == 1023) bsum[blockIdx.x] = incl;      // block total
}

__global__ void k_scanB(int* __restrict__ bsum, int NB) {   // NB <= 128
    __shared__ int lds[128];
    int t = threadIdx.x;
    int v = (t < NB) ? bsum[t] : 0;
    lds[t] = v; __syncthreads();
    for (int d = 1; d < 128; d <<= 1) {
        int x = (t >= d) ? lds[t - d] : 0; __syncthreads();
        lds[t] += x; __syncthreads();
    }
    if (t < NB) bsum[t] = lds[t] - v;            // exclusive block bases
}

// k2: EVERY block does gemm_self (64 rows -> permuted f32 self+bias in d_out)
// AND fill (1024 edges, no atomics). Edge vectors load early (drained by the
// staging barrier for free); the scattered ofs/bsum loads issue post-barrier
// to overlap MFMA; the uint2 scatter goes last.
__global__ __launch_bounds__(256) void k2_gemm_self_fill(
    const float* __restrict__ x, const unsigned short* __restrict__ WTs,
    const float* __restrict__ bias, int N,
    float* __restrict__ out,
    const int* __restrict__ src, const int* __restrict__ dst,
    const float* __restrict__ ew, const int* __restrict__ rank, int E,
    const int* __restrict__ ofs, const int* __restrict__ bsum,
    uint2* __restrict__ sorted) {
    __shared__ unsigned short sm[128 * 128];   // 32 KB (B1 half)
    int b = blockIdx.x;
    int tid = threadIdx.x;
    int e0 = b * 1024 + tid * 4;
    bool efull = (e0 + 3 < E);
    bool etail = !efull && (e0 < E);
    int4 d4 = make_int4(0,0,0,0), s4 = make_int4(0,0,0,0), r4 = make_int4(0,0,0,0);
    float4 w4 = make_float4(0.f,0.f,0.f,0.f);
    if (efull) {
        d4 = *(const int4*)(dst + e0);
        s4 = *(const int4*)(src + e0);
        w4 = *(const float4*)(ew + e0);
        r4 = *(const int4*)(rank + e0);
    }
    int brow = b * 64;
    bool gvalid = (brow < N);
    int w = tid >> 6, l = tid & 63;
    int c15 = l & 15;
    int kgrp = l >> 4;
    bf16x8 afrag[4];
    if (gvalid) {
        const uint4* gs = (const uint4*)WTs;
        uint4* ss = (uint4*)sm;
        uint4 st[8];
        #pragma unroll
        for (int r = 0; r < 8; ++r) st[r] = gs[2048 + r * 256 + tid];   // B1 half
        int arow = brow + w * 16 + c15;
        bool avalid = (arow < N);
        const float* xr = x + (size_t)arow * D;
        #pragma unroll
        for (int ks = 0; ks < 4; ++ks) {
            int k0 = ks * 32 + kgrp * 8;
            float4 a0, a1;
            if (avalid) { a0 = *(const float4*)(xr + k0); a1 = *(const float4*)(xr + k0 + 4); }
            else { a0 = make_float4(0.f, 0.f, 0.f, 0.f); a1 = a0; }
            bf16x8 f;
            f[0] = (__bf16)a0.x; f[1] = (__bf16)a0.y; f[2] = (__bf16)a0.z; f[3] = (__bf16)a0.w;
            f[4] = (__bf16)a1.x; f[5] = (__bf16)a1.y; f[6] = (__bf16)a1.z; f[7] = (__bf16)a1.w;
            afrag[ks] = f;
        }
        #pragma unroll
        for (int r = 0; r < 8; ++r) ss[r * 256 + tid] = st[r];
        __syncthreads();
    }
    // scattered position loads: overlap MFMA below
    int p0 = 0, p1 = 0, p2 = 0, p3 = 0;
    if (efull) {
        p0 = ofs[d4.x] + bsum[d4.x >> 10] + r4.x;
        p1 = ofs[d4.y] + bsum[d4.y >> 10] + r4.y;
        p2 = ofs[d4.z] + bsum[d4.z >> 10] + r4.z;
        p3 = ofs[d4.w] + bsum[d4.w >> 10] + r4.w;
    }
    if (gvalid) {
        f32x4 acc[8];
        #pragma unroll
        for (int nt = 0; nt < 8; ++nt) {
            int c = nt * 16 + c15;
            f32x4 a = {0.f, 0.f, 0.f, 0.f};
            #pragma unroll
            for (int ks = 0; ks < 4; ++ks) {
                int chunk = ks * 4 + kgrp;
                const bf16x8* bp = (const bf16x8*)(sm + c * 128 + ((chunk ^ c15) << 3));
                a = __builtin_amdgcn_mfma_f32_16x16x32_bf16(afrag[ks], *bp, a, 0, 0, 0);
            }
            acc[nt] = a;
        }
        float bv[8];
        #pragma unroll
        for (int nt = 0; nt < 8; ++nt) bv[nt] = bias[nt * 16 + c15];
        int orow = brow + w * 16 + kgrp * 4;
        #pragma unroll
        for (int j = 0; j < 4; ++j) {        // permuted f32 store; k_agg unpermutes
            int r = orow + j;
            if (r < N) {
                float4 s0 = make_float4(acc[0][j] + bv[0], acc[1][j] + bv[1],
                                        acc[2][j] + bv[2], acc[3][j] + bv[3]);
                float4 s1 = make_float4(acc[4][j] + bv[4], acc[5][j] + bv[5],
                                        acc[6][j] + bv[6], acc[7][j] + bv[7]);
                float4* op = (float4*)(out + (size_t)r * D + c15 * 8);
                op[0] = s0; op[1] = s1;
            }
        }
    }
    if (efull) {
        sorted[p0] = make_uint2((unsigned)s4.x, __float_as_uint(w4.x));
        sorted[p1] = make_uint2((unsigned)s4.y, __float_as_uint(w4.y));
        sorted[p2] = make_uint2((unsigned)s4.z, __float_as_uint(w4.z));
        sorted[p3] = make_uint2((unsigned)s4.w, __float_as_uint(w4.w));
    } else if (etail) {
        for (int e = e0; e < E; ++e) {
            int d = dst[e];
            sorted[ofs[d] + bsum[d >> 10] + rank[e]] =
                make_uint2((unsigned)src[e], __float_as_uint(ew[e]));
        }
    }
}

// One wave per destination node, 4 x 16-lane groups. Unroll-4 main loop:
// 4 sp-loads issue together, then 4 independent row-gathers in flight per
// group (16/wave). y is nt-major permuted: lane li's a_m is out col li+16m.
// out holds PERMUTED f32 self+bias (from k2): early-load, add, write
// unpermuted.
__global__ __launch_bounds__(256) void k_agg(
    const unsigned short* __restrict__ y, const uint2* __restrict__ sorted,
    const int* __restrict__ ofs, const int* __restrict__ bsum,
    const int* __restrict__ cnt, int N,
    float* __restrict__ out) {
    int w = threadIdx.x >> 6, l = threadIdx.x & 63;
    int node = blockIdx.x * 4 + w;
    if (node >= N) return;
    int s = ofs[node] + bsum[node >> 10], n = cnt[node];
    int g = l >> 4, li = l & 15;
    float4 s0, s1;
    if (l < 16) {   // early self-load (permuted)
        const float4* spf = (const float4*)(out + (size_t)node * D + li * 8);
        s0 = spf[0]; s1 = spf[1];
    }
    const uint2* sp = sorted + s;
    float a0 = 0.f, a1 = 0.f, a2 = 0.f, a3 = 0.f;
    float a4 = 0.f, a5 = 0.f, a6 = 0.f, a7 = 0.f;
    int j = g;
    for (; j + 12 < n; j += 16) {            // 4 edges/group/iter, 16 gathers/wave
        uint2 p0 = sp[j];
        uint2 p1 = sp[j + 4];
        uint2 p2 = sp[j + 8];
        uint2 p3 = sp[j + 12];
        uint4 v0 = *(const uint4*)(y + (size_t)p0.x * D + li * 8);
        uint4 v1 = *(const uint4*)(y + (size_t)p1.x * D + li * 8);
        uint4 v2 = *(const uint4*)(y + (size_t)p2.x * D + li * 8);
        uint4 v3 = *(const uint4*)(y + (size_t)p3.x * D + li * 8);
        float w0 = __uint_as_float(p0.y), w1 = __uint_as_float(p1.y);
        float w2 = __uint_as_float(p2.y), w3 = __uint_as_float(p3.y);
        a0 += w0 * bf2f(v0.x & 0xFFFFu); a1 += w0 * bf2f(v0.x >> 16);
        a2 += w0 * bf2f(v0.y & 0xFFFFu); a3 += w0 * bf2f(v0.y >> 16);
        a4 += w0 * bf2f(v0.z & 0xFFFFu); a5 += w0 * bf2f(v0.z >> 16);
        a6 += w0 * bf2f(v0.w & 0xFFFFu); a7 += w0 * bf2f(v0.w >> 16);
        a0 += w1 * bf2f(v1.x & 0xFFFFu); a1 += w1 * bf2f(v1.x >> 16);
        a2 += w1 * bf2f(v1.y & 0xFFFFu); a3 += w1 * bf2f(v1.y >> 16);
        a4 += w1 * bf2f(v1.z & 0xFFFFu); a5 += w1 * bf2f(v1.z >> 16);
        a6 += w1 * bf2f(v1.w & 0xFFFFu); a7 += w1 * bf2f(v1.w >> 16);
        a0 += w2 * bf2f(v2.x & 0xFFFFu); a1 += w2 * bf2f(v2.x >> 16);
        a2 += w2 * bf2f(v2.y & 0xFFFFu); a3 += w2 * bf2f(v2.y >> 16);
        a4 += w2 * bf2f(v2.z & 0xFFFFu); a5 += w2 * bf2f(v2.z >> 16);
        a6 += w2 * bf2f(v2.w & 0xFFFFu); a7 += w2 * bf2f(v2.w >> 16);
        a0 += w3 * bf2f(v3.x & 0xFFFFu); a1 += w3 * bf2f(v3.x >> 16);
        a2 += w3 * bf2f(v3.y & 0xFFFFu); a3 += w3 * bf2f(v3.y >> 16);
        a4 += w3 * bf2f(v3.z & 0xFFFFu); a5 += w3 * bf2f(v3.z >> 16);
        a6 += w3 * bf2f(v3.w & 0xFFFFu); a7 += w3 * bf2f(v3.w >> 16);
    }
    for (; j < n; j += 4) {                  // up to 3 tail edges per group
        uint2 p = sp[j];
        uint4 v = *(const uint4*)(y + (size_t)p.x * D + li * 8);
        float wt = __uint_as_float(p.y);
        a0 += wt * bf2f(v.x & 0xFFFFu); a1 += wt * bf2f(v.x >> 16);
        a2 += wt * bf2f(v.y & 0xFFFFu); a3 += wt * bf2f(v.y >> 16);
        a4 += wt * bf2f(v.z & 0xFFFFu); a5 += wt * bf2f(v.z >> 16);
        a6 += wt * bf2f(v.w & 0xFFFFu); a7 += wt * bf2f(v.w >> 16);
    }
    a0 += __shfl_xor(a0, 16, 64); a1 += __shfl_xor(a1, 16, 64);
    a2 += __shfl_xor(a2, 16, 64); a3 += __shfl_xor(a3, 16, 64);
    a4 += __shfl_xor(a4, 16, 64); a5 += __shfl_xor(a5, 16, 64);
    a6 += __shfl_xor(a6, 16, 64); a7 += __shfl_xor(a7, 16, 64);
    a0 += __shfl_xor(a0, 32, 64); a1 += __shfl_xor(a1, 32, 64);
    a2 += __shfl_xor(a2, 32, 64); a3 += __shfl_xor(a3, 32, 64);
    a4 += __shfl_xor(a4, 32, 64); a5 += __shfl_xor(a5, 32, 64);
    a6 += __shfl_xor(a6, 32, 64); a7 += __shfl_xor(a7, 32, 64);
    if (l < 16) {   // lane li owns cols li+16m; each m-group is one 64-B line
        float* op = out + (size_t)node * D + li;
        op[0]   = a0 + s0.x; op[16]  = a1 + s0.y;
        op[32]  = a2 + s0.z; op[48]  = a3 + s0.w;
        op[64]  = a4 + s1.x; op[80]  = a5 + s1.y;
        op[96]  = a6 + s1.z; op[112] = a7 + s1.w;
    }
}

extern "C" void kernel_launch(void* const* d_in, const int* in_sizes, int n_in,
                              void* d_out, int out_size, void* d_ws, size_t ws_size,
                              hipStream_t stream) {
    const float* x    = (const float*)d_in[0];
    const int*   esrc = (const int*)d_in[1];
    const int*   edst = (const int*)d_in[2];
    const float* ew   = (const float*)d_in[3];
    const float* Wn   = (const float*)d_in[4];
    const float* Wsf  = (const float*)d_in[5];
    const float* bias = (const float*)d_in[6];
    float* out = (float*)d_out;
    int N = in_sizes[0] / D;
    int E = in_sizes[1];

    char* ws = (char*)d_ws;
    size_t off = 0;
    unsigned short* WTs = (unsigned short*)(ws + off); off += 256 * 128 * sizeof(unsigned short);
    unsigned short* yb  = (unsigned short*)(ws + off); off += (size_t)N * D * sizeof(unsigned short);
    off = (off + 255) & ~(size_t)255;
    int* cnt  = (int*)(ws + off); off += (size_t)N * 4; off = (off + 255) & ~(size_t)255;
    int* ofs  = (int*)(ws + off); off += (size_t)N * 4; off = (off + 255) & ~(size_t)255;
    int* bsum = (int*)(ws + off); off += 1024;
    int* rank = (int*)(ws + off); off += (size_t)E * 4; off = (off + 255) & ~(size_t)255;
    uint2* sorted = (uint2*)(ws + off); off += (size_t)E * 8;

    k_build_wt<<<128, 256, 0, stream>>>(Wn, Wsf, WTs, cnt, N);

    int GB = (N + 63) / 64;                   // 1563
    int RB = (E + 1023) / 1024;               // 1563
    int M = (GB > RB ? GB : RB);
    k1_gemm_y_rank<<<M, 256, 0, stream>>>(x, WTs, N, yb, edst, E, cnt, rank);

    int NB = (N + 1023) / 1024;
    k_scanA<<<NB, 1024, 0, stream>>>(cnt, N, ofs, bsum);
    k_scanB<<<1, 128, 0, stream>>>(bsum, NB);

    k2_gemm_self_fill<<<M, 256, 0, stream>>>(x, WTs, bias, N, out,
                                             esrc, edst, ew, rank, E,
                                             ofs, bsum, sorted);

    k_agg<<<(N + 3) / 4, 256, 0, stream>>>(yb, sorted, ofs, bsum, cnt, N, out);
}